// Round 5
// baseline (77.579 us; speedup 1.0000x reference)
//
#include <hip/hip_runtime.h>
#include <utility>
#include <cstddef>

#define NROWS 16384      // B*S = 4*4096
#define CIN 32
#define X15_N (NROWS*CIN)
#define POSB 8           // positions per block
#define RED_BLOCKS 1024
#define PART_OFF 256
#define W_OFF 1536       // f32 Wsum[(v*32+C)*32+c], 4096 floats

typedef float f32x4 __attribute__((ext_vector_type(4)));
typedef short bf16x8 __attribute__((ext_vector_type(8)));

// ---------------- compile-time PGA(3,0,1) tables ----------------
// 0:1 1:e0 2:e1 3:e2 4:e3 5:e01 6:e02 7:e03 8:e12 9:e13 10:e23 11:e012 12:e013 13:e023 14:e123 15:e0123
constexpr int BITS_[16] = {0,1,2,4,8,3,5,9,6,10,12,7,11,13,14,15};

constexpr int idx_of(int bits) { int r = -1; for (int i = 0; i < 16; ++i) if (BITS_[i] == bits) r = i; return r; }

constexpr int sign_cat(int a, int b) {
  int sw = 0; a >>= 1;
  while (a) { sw += __builtin_popcount(a & b); a >>= 1; }
  return (sw & 1) ? -1 : 1;
}

constexpr int ds_(int i) { return sign_cat(BITS_[i], 15 ^ BITS_[i]); } // DUAL_SIGN

constexpr int geom_s(int i, int j) { int a = BITS_[i], b = BITS_[j]; return ((a & b & 1) == 0) ? sign_cat(a, b) : 0; }
constexpr int geom_m(int i, int j) { return idx_of(BITS_[i] ^ BITS_[j]); }

constexpr int tj_s(int i, int j) {
  int pa = BITS_[15 - i], qa = BITS_[15 - j];
  if (pa & qa) return 0;
  int m1 = idx_of(pa ^ qa);
  int jb = BITS_[15 - m1];
  if (jb & 1) return 0;
  return ds_(i) * ds_(j) * sign_cat(pa, qa) * ds_(m1) * sign_cat(15, jb);
}
constexpr int tj_m(int i, int j) {
  int pa = BITS_[15 - i], qa = BITS_[15 - j];
  int m1 = idx_of(pa ^ qa);
  int jb = BITS_[15 - m1];
  return idx_of(15 ^ jb);
}

// ---------------- unrolled sparse bilinear products ----------------
template <int I, int J>
__device__ __forceinline__ void acc_geom(float (&g)[16], const float (&x)[16], const float (&y)[16]) {
  constexpr int gs = geom_s(I, J);
  if constexpr (gs != 0) {
    constexpr int m = geom_m(I, J);
    if constexpr (gs > 0) g[m] = fmaf(x[I],  y[J], g[m]);
    else                  g[m] = fmaf(x[I], -y[J], g[m]);
  }
}
template <int I, int J>
__device__ __forceinline__ void acc_join(float (&g)[16], const float (&x)[16], const float (&y)[16]) {
  constexpr int js = tj_s(I, J);
  if constexpr (js != 0) {
    constexpr int m = tj_m(I, J);
    if constexpr (js > 0) g[m] = fmaf(x[I],  y[J], g[m]);
    else                  g[m] = fmaf(x[I], -y[J], g[m]);
  }
}
template <size_t... P>
__device__ __forceinline__ void all_geom(float (&g)[16], const float (&x)[16], const float (&y)[16], std::index_sequence<P...>) {
  (acc_geom<(int)(P / 16), (int)(P % 16)>(g, x, y), ...);
}
template <size_t... P>
__device__ __forceinline__ void all_join(float (&g)[16], const float (&x)[16], const float (&y)[16], std::index_sequence<P...>) {
  (acc_join<(int)(P / 16), (int)(P % 16)>(g, x, y), ...);
}

__device__ __forceinline__ unsigned short f2bf(float f) {
  unsigned int b = __float_as_uint(f);
  return (unsigned short)((b + 0x7FFFu + ((b >> 16) & 1u)) >> 16);
}
__device__ __forceinline__ float bf2f(unsigned short h) {
  return __uint_as_float(((unsigned int)h) << 16);
}

// ---------------- kernel 1: partial sums of x[...,15] ----------------
__global__ __launch_bounds__(256) void reduce_x15(const float* __restrict__ x, float* __restrict__ partials) {
  __shared__ float red[256];
  float s = 0.f;
  for (int i = blockIdx.x * 256 + threadIdx.x; i < X15_N; i += 256 * RED_BLOCKS)
    s += x[(long)i * 16 + 15];
  red[threadIdx.x] = s;
  __syncthreads();
  for (int off = 128; off > 0; off >>= 1) {
    if (threadIdx.x < off) red[threadIdx.x] += red[threadIdx.x + off];
    __syncthreads();
  }
  if (threadIdx.x == 0) partials[blockIdx.x] = red[0];
}

// ---------------- kernel 2: z15 finalize + f32 Wsum[(v*32+C)*32+c] ----------------
__global__ __launch_bounds__(256) void prep(const float* __restrict__ partials,
                                            const float* __restrict__ wjx, const float* __restrict__ wjy,
                                            const float* __restrict__ wgx, const float* __restrict__ wgy,
                                            float* __restrict__ wsv) {
  __shared__ float red[256];
  const int tid = threadIdx.x;
  red[tid] = partials[tid] + partials[tid + 256] + partials[tid + 512] + partials[tid + 768];
  __syncthreads();
  for (int off = 128; off > 0; off >>= 1) {
    if (tid < off) red[tid] += red[tid + off];
    __syncthreads();
  }
  if (tid == 0) wsv[0] = red[0] * (1.0f / (float)X15_N);

  for (int f = tid; f < 4096; f += 256) {   // f = (v*32 + C)*32 + c
    const int v = f >> 10, C = (f >> 5) & 31, cc = f & 31;
    const float* w = (v == 0) ? wjx : (v == 1) ? wjy : (v == 2) ? wgx : wgy;
    const float* wp = w + ((size_t)C * CIN + cc) * 9;
    float s = 0.f;
#pragma unroll
    for (int n = 0; n < 9; ++n) s += wp[n];
    wsv[W_OFF + f] = s;
  }
}

// ---------------- kernel 3: main (split-bf16 MFMA, unchained, R3 bounce) ----------------
__global__ __launch_bounds__(256) void ga_main(const float* __restrict__ x,
                                               const float* __restrict__ wsv,
                                               float* __restrict__ out) {
  __shared__ unsigned short sWh[128][32];      // [v*32+C][c] bf16 hi, 8 KB
  __shared__ unsigned short sWl[128][32];      // lo, 8 KB
  __shared__ unsigned short sUh[POSB][16][32]; // [pos][m][c] bf16 hi, 8 KB
  __shared__ unsigned short sUl[POSB][16][32]; // lo, 8 KB
  __shared__ float sB[POSB][32][2][16];        // bounce [pos][C][v][slot] (R3 layout), 32 KB

  const int tid = threadIdx.x;
  const float z15 = wsv[0];

  // stage W: load f32 sums, split hi/lo in-kernel
  {
    const float* wsrc = wsv + W_OFF;
    unsigned short* wh = &sWh[0][0];
    unsigned short* wl = &sWl[0][0];
#pragma unroll
    for (int f = tid; f < 4096; f += 256) {
      const float s = wsrc[f];
      const unsigned short h = f2bf(s);
      wh[f] = h;
      wl[f] = f2bf(s - bf2f(h));
    }
  }

  // stage U hi/lo: thread (pos, c) loads x row, builds u = x + x*e0
  const int pos = tid >> 5;
  const int c = tid & 31;
  const long row0 = (long)blockIdx.x * POSB;
  {
    const float4* xp = (const float4*)(x + ((row0 + pos) * CIN + c) * 16);
    const float4 a0 = xp[0], a1 = xp[1], a2 = xp[2], a3 = xp[3];
    float u[16];
    u[0]  = a0.x;        u[1]  = a0.y + a0.x; u[2]  = a0.z;        u[3]  = a0.w;
    u[4]  = a1.x;        u[5]  = a1.y - a0.z; u[6]  = a1.z - a0.w; u[7]  = a1.w - a1.x;
    u[8]  = a2.x;        u[9]  = a2.y;        u[10] = a2.z;        u[11] = a2.w + a2.x;
    u[12] = a3.x + a2.y; u[13] = a3.y + a2.z; u[14] = a3.z;        u[15] = a3.w - a3.z;
#pragma unroll
    for (int m = 0; m < 16; ++m) {
      const unsigned short h = f2bf(u[m]);
      sUh[pos][m][c] = h;
      sUl[pos][m][c] = f2bf(u[m] - bf2f(h));
    }
  }
  __syncthreads();

  const int lane = tid & 63;
  const int w = tid >> 6;          // wave 0..3 owns positions {2w, 2w+1}
  const int lm = lane & 15;
  const int lk = lane >> 4;
  const int p0 = 2 * w, p1 = 2 * w + 1;

#pragma unroll
  for (int pass = 0; pass < 2; ++pass) {
    // B-frags: Wt row = pass*64 + t*16 + lm, k-slice c = lk*8..+7
    bf16x8 bh[4], bl[4];
#pragma unroll
    for (int t = 0; t < 4; ++t) {
      bh[t] = *(const bf16x8*)&sWh[pass * 64 + t * 16 + lm][lk * 8];
      bl[t] = *(const bf16x8*)&sWl[pass * 64 + t * 16 + lm][lk * 8];
    }
    // A-frags
    const bf16x8 ah0 = *(const bf16x8*)&sUh[p0][lm][lk * 8];
    const bf16x8 al0 = *(const bf16x8*)&sUl[p0][lm][lk * 8];
    const bf16x8 ah1 = *(const bf16x8*)&sUh[p1][lm][lk * 8];
    const bf16x8 al1 = *(const bf16x8*)&sUl[p1][lm][lk * 8];

    f32x4 d0[4], d1[4];
#pragma unroll
    for (int t = 0; t < 4; ++t) {
      const f32x4 zz = {0.f, 0.f, 0.f, 0.f};
      f32x4 m0 = __builtin_amdgcn_mfma_f32_16x16x32_bf16(ah0, bh[t], zz, 0, 0, 0);
      f32x4 c0a = __builtin_amdgcn_mfma_f32_16x16x32_bf16(ah0, bl[t], zz, 0, 0, 0);
      f32x4 c0b = __builtin_amdgcn_mfma_f32_16x16x32_bf16(al0, bh[t], zz, 0, 0, 0);
      d0[t] = m0 + c0a + c0b;
      f32x4 m1 = __builtin_amdgcn_mfma_f32_16x16x32_bf16(ah1, bh[t], zz, 0, 0, 0);
      f32x4 c1a = __builtin_amdgcn_mfma_f32_16x16x32_bf16(ah1, bl[t], zz, 0, 0, 0);
      f32x4 c1b = __builtin_amdgcn_mfma_f32_16x16x32_bf16(al1, bh[t], zz, 0, 0, 0);
      d1[t] = m1 + c1a + c1b;
    }

    // bounce write (R3 layout): lane has D[m = lk*4+r][n = 16t+lm]; v = t>>1, C = (t&1)*16+lm
#pragma unroll
    for (int t = 0; t < 4; ++t) {
      const int Cw = (t & 1) * 16 + lm;
      const int vw = t >> 1;
      const int slot = lk ^ (Cw & 3);      // XOR-swizzle
      *(f32x4*)&sB[p0][Cw][vw][slot * 4] = d0[t];
      *(f32x4*)&sB[p1][Cw][vw][slot * 4] = d1[t];
    }
    __syncthreads();

    // epilogue (R3 gather): thread (pos, C=c)
    float xv[16], yv[16];
#pragma unroll
    for (int s = 0; s < 4; ++s) {
      const int mq = s ^ (c & 3);
      f32x4 qx = *(const f32x4*)&sB[pos][c][0][s * 4];
      f32x4 qy = *(const f32x4*)&sB[pos][c][1][s * 4];
#pragma unroll
      for (int e = 0; e < 4; ++e) { xv[mq * 4 + e] = qx[e]; yv[mq * 4 + e] = qy[e]; }
    }

    float r[16];
#pragma unroll
    for (int m = 0; m < 16; ++m) r[m] = 0.f;

    if (pass == 0) {
      all_join(r, xv, yv, std::make_index_sequence<256>{});
      float* ob = out + (((row0 + pos) * 64) + c) * 16;
      f32x4 o;
#pragma unroll
      for (int q = 0; q < 4; ++q) {
#pragma unroll
        for (int e = 0; e < 4; ++e) o[e] = r[q * 4 + e] * z15;
        *(f32x4*)(ob + q * 4) = o;
      }
    } else {
      all_geom(r, xv, yv, std::make_index_sequence<256>{});
      float* ob = out + (((row0 + pos) * 64) + 32 + c) * 16;
      f32x4 o;
#pragma unroll
      for (int q = 0; q < 4; ++q) {
#pragma unroll
        for (int e = 0; e < 4; ++e) o[e] = r[q * 4 + e];
        *(f32x4*)(ob + q * 4) = o;
      }
    }
    __syncthreads();   // sB reused by next pass
  }
}

extern "C" void kernel_launch(void* const* d_in, const int* in_sizes, int n_in,
                              void* d_out, int out_size, void* d_ws, size_t ws_size,
                              hipStream_t stream) {
  const float* x   = (const float*)d_in[0];
  const float* wjx = (const float*)d_in[1];
  const float* wjy = (const float*)d_in[2];
  const float* wgx = (const float*)d_in[3];
  const float* wgy = (const float*)d_in[4];
  float* out = (float*)d_out;
  float* wsv = (float*)d_ws;

  reduce_x15<<<RED_BLOCKS, 256, 0, stream>>>(x, wsv + PART_OFF);
  prep<<<1, 256, 0, stream>>>(wsv + PART_OFF, wjx, wjy, wgx, wgy, wsv);
  ga_main<<<NROWS / POSB, 256, 0, stream>>>(x, wsv, out);
}